// Round 14
// baseline (46.996 us; speedup 1.0000x reference)
//
#include <hip/hip_runtime.h>

// Backflow: out[b] = sum_d det(g[b,d]) * bf[d]
//   g[b,d][i][j] = sum_h h2[b,h]*Wg[h,d,sel[b,i],j] + bg[d,sel[b,i],j]
// B=8192, O=64, E=16, D=16, H=4.
//
// 128-thread blocks = 2 waves = 2 samples (dodges the ~16-WG/CU cap that
// pinned single-wave blocks at 4 waves/SIMD). Each wave: own 8KB LDS half.
//  LOAD role lane=r*4+c: coalesced Wg/bg rows, h2-weighted sum in regs,
//    staged to LDS; TWO dets per sched_barrier (halves exposed L2 latency).
//  LU role lane=4d+l: reads rows l,l+4,l+8,l+12 of det d from LDS; then
//    fully-unrolled triangular unpivoted LU (zero DS ops, static DPP
//    quad_perm broadcasts, column-shift, per-round array retirement).
// Retry (tau=1e-4*mat_max, rare): attempt loop RE-RUNS the same staged
// build (no separate gather code -> less VGPR/I$), applies M = I + 0.5*C16
// only to flagged quads (exec-masked DPP), block-uniform decision via LDS
// flag so __syncthreads stays uniform. det rescale 65536/65535 per quad.
// Lessons: R6 no min-waves bound (spill). R7 macro hygiene. R12 rule #20
// (runtime-indexed R arrays -> scratch). R13: VGPR cap works, 46us.

template <int CTRL>
__device__ __forceinline__ float dpp_movf(float v) {
    return __int_as_float(__builtin_amdgcn_update_dpp(
        0, __float_as_int(v), CTRL, 0xF, 0xF, true));
}

__global__ __launch_bounds__(128) void backflow_kernel(
    const float* __restrict__ x,    // (B,64)
    const float* __restrict__ W1,   // (64,4)
    const float* __restrict__ b1,   // (4,)
    const float* __restrict__ W2,   // (4,4)
    const float* __restrict__ b2,   // (4,)
    const float* __restrict__ Wg,   // (4,16,64,16)
    const float* __restrict__ bg,   // (16,64,16)
    const float* __restrict__ bf,   // (16,1)
    float* __restrict__ out,        // (B,)
    int B)
{
    const int lane  = threadIdx.x & 63;
    const int wavei = threadIdx.x >> 6;
    const int b     = blockIdx.x * 2 + wavei;
    const int d = lane >> 2;   // LU: det index; LOAD: row index r (same bits)
    const int l = lane & 3;    // LU: lane-in-quad; LOAD: chunk index c

    __shared__ float4 smem[1024];   // 16 KB: 2 waves x (8 dets x 16 rows x 4 chunks)
    __shared__ int s_retry;
    float4* const sm = smem + (wavei << 9);
    if (threadIdx.x == 0) s_retry = 0;
    if (b >= B) return;   // never taken at B=8192 (grid = B/2)

    // ---- occupied-orbital mask ----
    const float xv = x[b * 64 + lane];
    const unsigned long long mask = __ballot(xv != 0.0f);
    const bool empty = ((mask & ~1ull) == 0ull);

    // ---- h1 = relu(x @ W1 + b1): 64-lane butterfly ----
    const float4 w1 = reinterpret_cast<const float4*>(W1)[lane];
    float c0 = xv * w1.x, c1 = xv * w1.y, c2 = xv * w1.z, c3 = xv * w1.w;
    #pragma unroll
    for (int off = 32; off >= 1; off >>= 1) {
        c0 += __shfl_xor(c0, off);
        c1 += __shfl_xor(c1, off);
        c2 += __shfl_xor(c2, off);
        c3 += __shfl_xor(c3, off);
    }
    const float h10 = fmaxf(c0 + b1[0], 0.0f);
    const float h11 = fmaxf(c1 + b1[1], 0.0f);
    const float h12 = fmaxf(c2 + b1[2], 0.0f);
    const float h13 = fmaxf(c3 + b1[3], 0.0f);

    // ---- h2 = relu(h1 @ W2 + b2) ----
    float h2[4];
    #pragma unroll
    for (int j = 0; j < 4; ++j) {
        float v = b2[j];
        v = fmaf(h10, W2[0 * 4 + j], v);
        v = fmaf(h11, W2[1 * 4 + j], v);
        v = fmaf(h12, W2[2 * 4 + j], v);
        v = fmaf(h13, W2[3 * 4 + j], v);
        h2[j] = fmaxf(v, 0.0f);
    }

    // ---- LOAD-role selected row: sel_r for r = lane>>2 (skip r set bits) ----
    unsigned long long mr = mask;
    #pragma unroll
    for (int i = 0; i < 15; ++i) if (i < d) mr &= mr - 1;
    const int selr = mr ? (int)__builtin_ctzll(mr) : 0;
    const int rowoff = selr * 4 + l;   // float4 index: row selr, chunk c=l

    const float4* wgp = reinterpret_cast<const float4*>(Wg);
    const float4* bgp = reinterpret_cast<const float4*>(bg);

    float R0[16], R1[16], R2[16], R3[16];

    // ---- one det's coalesced build + LDS stage (arithmetic order = R13) ----
#define STAGE_ONE(DS) do {                                                   \
        const int _ds = (DS);                                                \
        const float4 wb  = bgp[_ds * 256 + rowoff];                          \
        const float4 w3  = wgp[(48 + _ds) * 256 + rowoff];                   \
        const float4 w2c = wgp[(32 + _ds) * 256 + rowoff];                   \
        const float4 wv1 = wgp[(16 + _ds) * 256 + rowoff];                   \
        const float4 w0  = wgp[_ds * 256 + rowoff];                          \
        float4 a;                                                            \
        a.x = fmaf(h2[0],w0.x, fmaf(h2[1],wv1.x, fmaf(h2[2],w2c.x, fmaf(h2[3],w3.x, wb.x)))); \
        a.y = fmaf(h2[0],w0.y, fmaf(h2[1],wv1.y, fmaf(h2[2],w2c.y, fmaf(h2[3],w3.y, wb.y)))); \
        a.z = fmaf(h2[0],w0.z, fmaf(h2[1],wv1.z, fmaf(h2[2],w2c.z, fmaf(h2[3],w3.z, wb.z)))); \
        a.w = fmaf(h2[0],w0.w, fmaf(h2[1],wv1.w, fmaf(h2[2],w2c.w, fmaf(h2[3],w3.w, wb.w)))); \
        sm[(_ds & 7) * 64 + d * 4 + (l ^ (_ds & 3))] = a;                    \
    } while (0)

#define RD_ROWS(RW, S) do { _Pragma("unroll")                                \
        for (int q = 0; q < 4; ++q) {                                        \
            const float4 t = sm[(d & 7) * 64 + (l + 4 * (S)) * 4 + (q ^ (d & 3))]; \
            RW[q*4+0] = t.x; RW[q*4+1] = t.y;                                \
            RW[q*4+2] = t.z; RW[q*4+3] = t.w;                                \
        } } while (0)

#define STAGE_AND_READ do {                                                  \
        _Pragma("unroll 1")                                                  \
        for (int half = 0; half < 2; ++half) {                               \
            _Pragma("unroll 1")                                              \
            for (int dp = 0; dp < 4; ++dp) {   /* 2 dets in flight */        \
                STAGE_ONE(half * 8 + 2 * dp);                                \
                STAGE_ONE(half * 8 + 2 * dp + 1);                            \
                __builtin_amdgcn_sched_barrier(0);                           \
            }                                                                \
            __syncthreads();                                                 \
            if ((d >> 3) == half) {                                          \
                RD_ROWS(R0, 0);                                              \
                RD_ROWS(R1, 1);                                              \
                RD_ROWS(R2, 2);                                              \
                RD_ROWS(R3, 3);                                              \
            }                                                                \
            __syncthreads();                                                 \
        } } while (0)

    // ---- triangular unpivoted LU steps (K static everywhere) ----
#define STEP4(K, DAC, PA, PB, PC, PD) do {                                   \
        const float pivot = dpp_movf<((K) & 3) * 0x55>(PA[0]);               \
        nb += !(fabsf(pivot) >= tau);                                        \
        DAC *= (double)pivot;                                                \
        const float pinv = __builtin_amdgcn_rcpf(pivot);                     \
        const float fa = (l > ((K) & 3)) ? PA[0] * pinv : 0.0f;              \
        const float fb = PB[0] * pinv;                                       \
        const float fc = PC[0] * pinv;                                       \
        const float fd = PD[0] * pinv;                                       \
        _Pragma("unroll")                                                    \
        for (int j = 1; j <= 15 - (K); ++j) {                                \
            const float pv = dpp_movf<((K) & 3) * 0x55>(PA[j]);              \
            PA[j - 1] = fmaf(-fa, pv, PA[j]);                                \
            PB[j - 1] = fmaf(-fb, pv, PB[j]);                                \
            PC[j - 1] = fmaf(-fc, pv, PC[j]);                                \
            PD[j - 1] = fmaf(-fd, pv, PD[j]);                                \
        } } while (0)

#define STEP3(K, DAC, PA, PB, PC) do {                                       \
        const float pivot = dpp_movf<((K) & 3) * 0x55>(PA[0]);               \
        nb += !(fabsf(pivot) >= tau);                                        \
        DAC *= (double)pivot;                                                \
        const float pinv = __builtin_amdgcn_rcpf(pivot);                     \
        const float fa = (l > ((K) & 3)) ? PA[0] * pinv : 0.0f;              \
        const float fb = PB[0] * pinv;                                       \
        const float fc = PC[0] * pinv;                                       \
        _Pragma("unroll")                                                    \
        for (int j = 1; j <= 15 - (K); ++j) {                                \
            const float pv = dpp_movf<((K) & 3) * 0x55>(PA[j]);              \
            PA[j - 1] = fmaf(-fa, pv, PA[j]);                                \
            PB[j - 1] = fmaf(-fb, pv, PB[j]);                                \
            PC[j - 1] = fmaf(-fc, pv, PC[j]);                                \
        } } while (0)

#define STEP2(K, DAC, PA, PB) do {                                           \
        const float pivot = dpp_movf<((K) & 3) * 0x55>(PA[0]);               \
        nb += !(fabsf(pivot) >= tau);                                        \
        DAC *= (double)pivot;                                                \
        const float pinv = __builtin_amdgcn_rcpf(pivot);                     \
        const float fa = (l > ((K) & 3)) ? PA[0] * pinv : 0.0f;              \
        const float fb = PB[0] * pinv;                                       \
        _Pragma("unroll")                                                    \
        for (int j = 1; j <= 15 - (K); ++j) {                                \
            const float pv = dpp_movf<((K) & 3) * 0x55>(PA[j]);              \
            PA[j - 1] = fmaf(-fa, pv, PA[j]);                                \
            PB[j - 1] = fmaf(-fb, pv, PB[j]);                                \
        } } while (0)

#define STEP1(K, DAC, PA) do {                                               \
        const float pivot = dpp_movf<((K) & 3) * 0x55>(PA[0]);               \
        nb += !(fabsf(pivot) >= tau);                                        \
        DAC *= (double)pivot;                                                \
        const float pinv = __builtin_amdgcn_rcpf(pivot);                     \
        const float fa = (l > ((K) & 3)) ? PA[0] * pinv : 0.0f;              \
        _Pragma("unroll")                                                    \
        for (int j = 1; j <= 15 - (K); ++j) {                                \
            const float pv = dpp_movf<((K) & 3) * 0x55>(PA[j]);              \
            PA[j - 1] = fmaf(-fa, pv, PA[j]);                                \
        } } while (0)

    double deta = 1.0, detb = 1.0;
    bool domix = false;

    #pragma unroll 1
    for (int attempt = 0; attempt < 2; ++attempt) {
        STAGE_AND_READ;

        if (domix) {   // exec-masked per quad (quad-uniform), DPP-only:
            // rows_new[i] = rows[i] + 0.5*rows[(i+1)%16]; receiver pulls from
            // lane (l+1)&3 (quad_perm[1,2,3,0]=0x39); lane 0 presents slot+1.
            const bool z = (l == 0);
            #pragma unroll
            for (int j = 0; j < 16; ++j) {
                const float w0 = z ? R1[j] : R0[j];
                const float wv = z ? R2[j] : R1[j];
                const float w2 = z ? R3[j] : R2[j];
                const float w3 = z ? R0[j] : R3[j];
                R0[j] = fmaf(0.5f, dpp_movf<0x39>(w0), R0[j]);
                R1[j] = fmaf(0.5f, dpp_movf<0x39>(wv), R1[j]);
                R2[j] = fmaf(0.5f, dpp_movf<0x39>(w2), R2[j]);
                R3[j] = fmaf(0.5f, dpp_movf<0x39>(w3), R3[j]);
            }
        }

        // ---- matrix scale for pivot-quality flag (quad-uniform) ----
        float mm = 0.0f;
        #pragma unroll
        for (int j = 0; j < 16; ++j) {
            mm = fmaxf(mm, fmaxf(fmaxf(fabsf(R0[j]), fabsf(R1[j])),
                                 fmaxf(fabsf(R2[j]), fabsf(R3[j]))));
        }
        mm = fmaxf(mm, dpp_movf<0xB1>(mm));   // quad_perm[1,0,3,2]
        mm = fmaxf(mm, dpp_movf<0x4E>(mm));   // quad_perm[2,3,0,1]
        const float tau = 1e-4f * mm;

        deta = 1.0; detb = 1.0;
        int nb = 0;

        STEP4(0,  deta, R0, R1, R2, R3);
        STEP4(1,  detb, R0, R1, R2, R3);
        STEP4(2,  deta, R0, R1, R2, R3);
        STEP4(3,  detb, R0, R1, R2, R3);
        STEP3(4,  deta, R1, R2, R3);
        STEP3(5,  detb, R1, R2, R3);
        STEP3(6,  deta, R1, R2, R3);
        STEP3(7,  detb, R1, R2, R3);
        STEP2(8,  deta, R2, R3);
        STEP2(9,  detb, R2, R3);
        STEP2(10, deta, R2, R3);
        STEP2(11, detb, R2, R3);
        STEP1(12, deta, R3);
        STEP1(13, detb, R3);
        STEP1(14, deta, R3);
        STEP1(15, detb, R3);

        if (attempt == 0) {
            if (nb != 0) s_retry = 1;        // any flagged lane (race-same-value OK)
            __syncthreads();                 // uniform: publish decision
            if (!s_retry) break;             // block-uniform break
            domix = (nb != 0);               // only flagged quads get the mix
        }
    }
#undef STEP1
#undef STEP2
#undef STEP3
#undef STEP4
#undef STAGE_AND_READ
#undef RD_ROWS
#undef STAGE_ONE

    // ---- combine: det_d (uniform in quad) dotted with bf ----
    float detf = (float)(deta * detb);
    if (domix) detf *= (65536.0f / 65535.0f);   // / det(I + 0.5*C16)
    float acc = (l == 0) ? detf * bf[d] : 0.0f;
    acc += __shfl_xor(acc, 4);
    acc += __shfl_xor(acc, 8);
    acc += __shfl_xor(acc, 16);
    acc += __shfl_xor(acc, 32);
    if (lane == 0) out[b] = empty ? 0.0f : acc;
}

extern "C" void kernel_launch(void* const* d_in, const int* in_sizes, int n_in,
                              void* d_out, int out_size, void* d_ws, size_t ws_size,
                              hipStream_t stream) {
    const float* x  = (const float*)d_in[0];
    const float* W1 = (const float*)d_in[1];
    const float* b1 = (const float*)d_in[2];
    const float* W2 = (const float*)d_in[3];
    const float* b2 = (const float*)d_in[4];
    const float* Wg = (const float*)d_in[5];
    const float* bg = (const float*)d_in[6];
    const float* bf = (const float*)d_in[7];
    float* out = (float*)d_out;

    const int B = in_sizes[0] / 64;
    const int blocks = (B + 1) / 2;   // 2 samples (waves) per 128-thread block
    backflow_kernel<<<blocks, 128, 0, stream>>>(x, W1, b1, W2, b2, Wg, bg, bf, out, B);
}